// Round 1
// baseline (1052.402 us; speedup 1.0000x reference)
//
#include <hip/hip_runtime.h>
#include <math.h>

#define BB 8
#define DD 512
#define NN 4096
#define KK 2048
#define MM (BB*NN)   // 32768 queries

#define TM 64        // queries per block
#define TK 128       // codes per K-tile
#define DC 32        // d-chunk
#define ESTRIDE (TK+4)  // pad keeps 16B alignment (528B row) + bank spread

// halfe2[k] = 0.5 * sum_d embed[k,d]^2   (one wave per row, 4 rows/block)
__global__ void e2_half_kernel(const float* __restrict__ embed,
                               float* __restrict__ halfe2) {
  int row  = blockIdx.x * 4 + (threadIdx.x >> 6);
  int lane = threadIdx.x & 63;
  const float* e = embed + (size_t)row * DD;
  float s = 0.f;
  #pragma unroll
  for (int i = 0; i < DD/64; ++i) { float v = e[lane + 64*i]; s += v*v; }
  #pragma unroll
  for (int off = 32; off >= 1; off >>= 1) s += __shfl_xor(s, off, 64);
  if (lane == 0) halfe2[row] = 0.5f * s;
}

// Fused GEMM + argmin + gather.
// score[m,k] = 0.5*e2[k] - <x_m, e_k>  (same argmin as x2 - 2<x,e> + e2)
__global__ __launch_bounds__(256, 2)
void vq_kernel(const float* __restrict__ x,
               const float* __restrict__ embed,
               const float* __restrict__ halfe2,
               float* __restrict__ out) {
  __shared__ float xs[DC][TM];       // xs[d][m]
  __shared__ float es[DC][ESTRIDE];  // es[d][k] (transposed embed chunk)
  __shared__ int   idx_s[TM];

  const int t  = threadIdx.x;
  const int tx = t & 15;
  const int ty = t >> 4;

  const int m0 = blockIdx.x * TM;     // global query base (never straddles batch: 64|4096)
  const int b  = m0 >> 12;            // /4096
  const int n0 = m0 & (NN - 1);
  const float* xbase = x + (size_t)b * DD * NN + n0;  // x[b, d, n0+m] = xbase[d*NN + m]

  float bestv[4];
  int   besti[4];
  #pragma unroll
  for (int i = 0; i < 4; ++i) { bestv[i] = INFINITY; besti[i] = 0; }

  for (int kt = 0; kt < KK/TK; ++kt) {   // 16 K-tiles
    float acc[4][8];
    #pragma unroll
    for (int i = 0; i < 4; ++i)
      #pragma unroll
      for (int j = 0; j < 8; ++j) acc[i][j] = 0.f;

    for (int dc = 0; dc < DD/DC; ++dc) { // 16 d-chunks
      __syncthreads();  // WAR: prior chunk's readers done before restage
      // stage x chunk: coalesced over n (contiguous inner dim of x)
      #pragma unroll
      for (int i = 0; i < (DC*TM)/256; ++i) {   // 8
        int l = t + 256*i;
        int d = l >> 6;
        int m = l & 63;
        xs[d][m] = xbase[(size_t)(dc*DC + d) * NN + m];
      }
      // stage embed chunk transposed: float4 reads along d (contiguous rows)
      const float* ebase = embed + (size_t)(kt*TK) * DD + dc*DC;
      #pragma unroll
      for (int i = 0; i < (DC*TK)/(256*4); ++i) {  // 4 float4/thread
        int l = t + 256*i;          // float4 id, 0..1023
        int k = l >> 3;             // 8 float4 per code row
        int f = l & 7;
        const float4 v = *(const float4*)(ebase + (size_t)k * DD + 4*f);
        es[4*f+0][k] = v.x;
        es[4*f+1][k] = v.y;
        es[4*f+2][k] = v.z;
        es[4*f+3][k] = v.w;
      }
      __syncthreads();
      // 4x8 register microtile; a-read is 16-lane broadcast, b-reads stride-4 spread
      #pragma unroll
      for (int d = 0; d < DC; ++d) {
        const float4 a4 = *(const float4*)&xs[d][ty*4];
        const float4 b0 = *(const float4*)&es[d][tx*4];
        const float4 b1 = *(const float4*)&es[d][64 + tx*4];
        const float a[4]  = {a4.x, a4.y, a4.z, a4.w};
        const float bb[8] = {b0.x, b0.y, b0.z, b0.w, b1.x, b1.y, b1.z, b1.w};
        #pragma unroll
        for (int i = 0; i < 4; ++i)
          #pragma unroll
          for (int j = 0; j < 8; ++j)
            acc[i][j] = fmaf(a[i], bb[j], acc[i][j]);
      }
    }

    // per-K-tile argmin epilogue (thread k-frag: {kb0..kb0+3} U {kb1..kb1+3})
    const int kb0 = kt*TK + tx*4;
    const int kb1 = kt*TK + 64 + tx*4;
    const float4 h0 = *(const float4*)&halfe2[kb0];
    const float4 h1 = *(const float4*)&halfe2[kb1];
    const float hh[8] = {h0.x, h0.y, h0.z, h0.w, h1.x, h1.y, h1.z, h1.w};
    #pragma unroll
    for (int i = 0; i < 4; ++i) {
      float v  = hh[0] - acc[i][0];
      int   vi = kb0;
      #pragma unroll
      for (int j = 1; j < 8; ++j) {
        float w  = hh[j] - acc[i][j];
        int   wk = (j < 4) ? (kb0 + j) : (kb1 + j - 4);
        if (w < v) { v = w; vi = wk; }   // strict <: first-index tie-break (k ascending)
      }
      // reduce across the 16 tx lanes (contiguous within quarter-wave)
      #pragma unroll
      for (int off = 1; off < 16; off <<= 1) {
        float ov = __shfl_xor(v, off, 64);
        int   oi = __shfl_xor(vi, off, 64);
        if (ov < v || (ov == v && oi < vi)) { v = ov; vi = oi; }
      }
      if (tx == 0) {
        if (v < bestv[i] || (v == bestv[i] && vi < besti[i])) {
          bestv[i] = v; besti[i] = vi;
        }
      }
    }
  }

  __syncthreads();
  if (tx == 0) {
    #pragma unroll
    for (int i = 0; i < 4; ++i) idx_s[ty*4 + i] = besti[i];
  }
  __syncthreads();

  // output 1: indices as float, flat offset M*D
  if (t < TM) {
    out[(size_t)MM * DD + m0 + t] = (float)idx_s[t];
  }

  // output 0: quantize[b,d,n] = embed[idx[m], d]; stores coalesced over n,
  // embed gather reads hit L2 (4 MB resident)
  float* qbase = out + (size_t)b * DD * NN + n0;
  for (int l = t; l < DD*TM; l += 256) {
    int d = l >> 6;
    int m = l & 63;
    qbase[(size_t)d * NN + m] = embed[(size_t)idx_s[m] * DD + d];
  }
}

extern "C" void kernel_launch(void* const* d_in, const int* in_sizes, int n_in,
                              void* d_out, int out_size, void* d_ws, size_t ws_size,
                              hipStream_t stream) {
  const float* x     = (const float*)d_in[0];   // [8, 512, 4096] fp32
  const float* embed = (const float*)d_in[1];   // [2048, 512] fp32
  float* out    = (float*)d_out;                // [8*512*4096] quantize + [32768] idx-as-float
  float* halfe2 = (float*)d_ws;                 // 2048 floats scratch

  hipLaunchKernelGGL(e2_half_kernel, dim3(KK/4), dim3(256), 0, stream, embed, halfe2);
  hipLaunchKernelGGL(vq_kernel, dim3(MM/TM), dim3(256), 0, stream,
                     x, embed, halfe2, out);
}

// Round 2
// 904.405 us; speedup vs baseline: 1.1636x; 1.1636x over previous
//
#include <hip/hip_runtime.h>
#include <math.h>

#define DDIM 512
#define NNN  4096
#define KKK  2048
#define MMM  32768          // 8*4096 queries

#define TMQ  128            // queries per block
#define TNC  128            // codes per k-tile
#define BKD  64             // d per staging round
#define KSPLIT 2
#define KHALF (KKK/KSPLIT)  // 1024 codes per block
#define NKT   (KHALF/TNC)   // 8 k-tiles per block
#define NDR   (DDIM/BKD)    // 8 d-rounds per k-tile
#define TAU   0.03f         // ambiguity margin (score units = dist/2); worst-case split err < 4e-3
#define CAPF  2048

// scratch layout inside d_out's quantize region (fully overwritten by the final gather):
#define PART_OFF 0                          // [q][ks][4] floats: 32768*2*4 = 1 MB
#define KEY_OFF  (MMM*8)                    // 262144 floats: 32768 u64 sortable keys
#define LIST_OFF (KEY_OFF + MMM*2)          // 327680: flagged-query list (ints)
#define CNT_OFF  (LIST_OFF + CAPF)          // 329728: atomic counter (int)
#define IDX_OFF  ((size_t)MMM * DDIM)       // 16777216: output 1 (indices as float)

typedef short short4v __attribute__((ext_vector_type(4)));
typedef short short8v __attribute__((ext_vector_type(8)));
typedef float f32x4   __attribute__((ext_vector_type(4)));

__device__ inline unsigned short f2bf(float f) {          // fp32 -> bf16 RNE
  unsigned u = __float_as_uint(f);
  u = u + 0x7FFFu + ((u >> 16) & 1u);
  return (unsigned short)(u >> 16);
}
__device__ inline float bf2f(unsigned short h) { return __uint_as_float(((unsigned)h) << 16); }

// XOR-swizzled short-index into a [128 rows][64 bf16] LDS tile.
// 16B-quad phys = quad ^ (row&7): rows 16B-aligned, uniform bank usage for
// b64 staging writes and b128 fragment reads.
__device__ inline int swz(int m, int d) {
  return m*64 + (((d >> 3) ^ (m & 7)) << 3) + (d & 7);
}

// ---------------- halfe2[k] = 0.5*||embed_k||^2 (+ zero the flag counter) ----
__global__ void e2_half_kernel(const float* __restrict__ embed,
                               float* __restrict__ halfe2,
                               float* __restrict__ out) {
  if (blockIdx.x == 0 && threadIdx.x == 0) *(int*)&out[CNT_OFF] = 0;
  int row  = blockIdx.x * 4 + (threadIdx.x >> 6);
  int lane = threadIdx.x & 63;
  const float* e = embed + (size_t)row * DDIM;
  float s = 0.f;
  #pragma unroll
  for (int i = 0; i < DDIM/64; ++i) { float v = e[lane + 64*i]; s += v*v; }
  #pragma unroll
  for (int off = 32; off >= 1; off >>= 1) s += __shfl_xor(s, off, 64);
  if (lane == 0) halfe2[row] = 0.5f * s;
}

// ---------------- main: 3-pass split-bf16 MFMA GEMM + fused argmin ----------
// score[q][k] = 0.5*||e_k||^2 - <x_q, e_k>; cross ~= xh*eh + xh*el + xl*eh
__global__ __launch_bounds__(256, 2)
void vq_main(const float* __restrict__ x, const float* __restrict__ embed,
             const float* __restrict__ halfe2, float* __restrict__ out) {
  __shared__ __align__(16) short sm[4*TMQ*BKD];   // 64 KB: xs_h|xs_l|es_h|es_l
  short* xs_h = sm;
  short* xs_l = sm + TMQ*BKD;
  short* es_h = sm + 2*TMQ*BKD;
  short* es_l = sm + 3*TMQ*BKD;

  const int t    = threadIdx.x;
  const int mb   = blockIdx.x >> 1;
  const int ks   = blockIdx.x & 1;
  const int q0   = mb * TMQ;
  const int bb   = q0 >> 12;
  const int n0   = q0 & (NNN - 1);
  const int kbase= ks * KHALF;
  const int w    = t >> 6, lane = t & 63;
  const int mw   = (w >> 1) * 64, nw = (w & 1) * 64;  // wave 64x64 sub-tile
  const int l15  = lane & 15, lg = lane >> 4;

  const float* xb = x + (size_t)bb * DDIM * NNN + n0;

  // running (best, best-idx, 2nd-best) per (mi,r) = 16 queries/lane
  float rv1[16], rv2[16]; int ri1[16];
  #pragma unroll
  for (int i = 0; i < 16; ++i) { rv1[i] = INFINITY; rv2[i] = INFINITY; ri1[i] = 0x7FFFFFFF; }

  const int xm  = t & 127;           // x staging: query row
  const int xdg = (t >> 7) * 32;     // x staging: d half

  for (int kt = 0; kt < NKT; ++kt) {
    const int kb = kbase + kt * TNC;
    f32x4 acc[4][4];
    #pragma unroll
    for (int mi = 0; mi < 4; ++mi)
      #pragma unroll
      for (int ni = 0; ni < 4; ++ni)
        acc[mi][ni] = (f32x4){0.f, 0.f, 0.f, 0.f};

    for (int dr = 0; dr < NDR; ++dr) {
      const int d0 = dr * BKD;
      __syncthreads();
      // ---- stage x tile (transpose [d][n] -> [m][d]), split hi/lo, b64 LDS writes
      #pragma unroll
      for (int i = 0; i < 8; ++i) {
        const int dl = xdg + 4*i;
        const float v0 = xb[(size_t)(d0+dl+0)*NNN + xm];
        const float v1 = xb[(size_t)(d0+dl+1)*NNN + xm];
        const float v2 = xb[(size_t)(d0+dl+2)*NNN + xm];
        const float v3 = xb[(size_t)(d0+dl+3)*NNN + xm];
        const unsigned short h0=f2bf(v0),h1=f2bf(v1),h2=f2bf(v2),h3=f2bf(v3);
        short4v hi = {(short)h0,(short)h1,(short)h2,(short)h3};
        short4v lo = {(short)f2bf(v0-bf2f(h0)), (short)f2bf(v1-bf2f(h1)),
                      (short)f2bf(v2-bf2f(h2)), (short)f2bf(v3-bf2f(h3))};
        *(short4v*)&xs_h[swz(xm, dl)] = hi;
        *(short4v*)&xs_l[swz(xm, dl)] = lo;
      }
      // ---- stage embed tile (rows contiguous: float4 loads), split hi/lo
      #pragma unroll
      for (int i = 0; i < 8; ++i) {
        const int fid = t + 256*i;
        const int k   = fid >> 4;
        const int dl  = (fid & 15) * 4;
        const float4 v = *(const float4*)&embed[(size_t)(kb + k)*DDIM + d0 + dl];
        const unsigned short h0=f2bf(v.x),h1=f2bf(v.y),h2=f2bf(v.z),h3=f2bf(v.w);
        short4v hi = {(short)h0,(short)h1,(short)h2,(short)h3};
        short4v lo = {(short)f2bf(v.x-bf2f(h0)), (short)f2bf(v.y-bf2f(h1)),
                      (short)f2bf(v.z-bf2f(h2)), (short)f2bf(v.w-bf2f(h3))};
        *(short4v*)&es_h[swz(k, dl)] = hi;
        *(short4v*)&es_l[swz(k, dl)] = lo;
      }
      __syncthreads();
      // ---- 2 k-steps of 32 d; 48 MFMAs per step per wave
      #pragma unroll
      for (int kk = 0; kk < 2; ++kk) {
        const int dk = kk*32 + lg*8;
        short8v bh[4], bl[4];
        #pragma unroll
        for (int ni = 0; ni < 4; ++ni) {
          bh[ni] = *(short8v*)&es_h[swz(nw + ni*16 + l15, dk)];
          bl[ni] = *(short8v*)&es_l[swz(nw + ni*16 + l15, dk)];
        }
        #pragma unroll
        for (int mi = 0; mi < 4; ++mi) {
          const short8v ah = *(short8v*)&xs_h[swz(mw + mi*16 + l15, dk)];
          const short8v al = *(short8v*)&xs_l[swz(mw + mi*16 + l15, dk)];
          #pragma unroll
          for (int ni = 0; ni < 4; ++ni) {
            acc[mi][ni] = __builtin_amdgcn_mfma_f32_16x16x32_bf16(ah, bh[ni], acc[mi][ni], 0, 0, 0);
            acc[mi][ni] = __builtin_amdgcn_mfma_f32_16x16x32_bf16(ah, bl[ni], acc[mi][ni], 0, 0, 0);
            acc[mi][ni] = __builtin_amdgcn_mfma_f32_16x16x32_bf16(al, bh[ni], acc[mi][ni], 0, 0, 0);
          }
        }
      }
    }

    // ---- per-k-tile argmin epilogue; C/D: col=lane&15 (code), row=lg*4+r (query)
    float he[4];
    #pragma unroll
    for (int ni = 0; ni < 4; ++ni) he[ni] = halfe2[kb + nw + ni*16 + l15];
    #pragma unroll
    for (int mi = 0; mi < 4; ++mi) {
      #pragma unroll
      for (int r = 0; r < 4; ++r) {
        float v1 = INFINITY, v2 = INFINITY; int i1 = 0x7FFFFFFF;
        #pragma unroll
        for (int ni = 0; ni < 4; ++ni) {
          const float sc = he[ni] - acc[mi][ni][r];
          const int   ci = kb + nw + ni*16 + l15;
          if (sc < v1 || (sc == v1 && ci < i1)) { v2 = v1; v1 = sc; i1 = ci; }
          else v2 = fminf(v2, sc);
        }
        #pragma unroll
        for (int off = 1; off < 16; off <<= 1) {   // merge 16 code-columns (lanes)
          const float ov1 = __shfl_xor(v1, off, 64);
          const int   oi1 = __shfl_xor(i1, off, 64);
          const float ov2 = __shfl_xor(v2, off, 64);
          if (ov1 < v1 || (ov1 == v1 && oi1 < i1)) { v2 = fminf(v1, ov2); v1 = ov1; i1 = oi1; }
          else v2 = fminf(v2, ov1);
        }
        const int e_ = mi*4 + r;
        if (v1 < rv1[e_] || (v1 == rv1[e_] && i1 < ri1[e_])) {
          rv2[e_] = fminf(rv1[e_], v2); rv1[e_] = v1; ri1[e_] = i1;
        } else rv2[e_] = fminf(rv2[e_], v1);
      }
    }
  }

  // ---- merge the two code-half waves per query via LDS, store partial triple
  __syncthreads();
  float* mbuf = (float*)sm;   // [128 q][2 halves][3]
  if (l15 == 0) {
    #pragma unroll
    for (int mi = 0; mi < 4; ++mi)
      #pragma unroll
      for (int r = 0; r < 4; ++r) {
        const int ql = mw + mi*16 + lg*4 + r;
        const int slot = (ql*2 + (w & 1))*3;
        const int e_ = mi*4 + r;
        mbuf[slot+0] = rv1[e_];
        mbuf[slot+1] = __int_as_float(ri1[e_]);
        mbuf[slot+2] = rv2[e_];
      }
  }
  __syncthreads();
  if (t < TMQ) {
    const float a1 = mbuf[t*6+0]; const int ai = __float_as_int(mbuf[t*6+1]); const float a2 = mbuf[t*6+2];
    const float b1 = mbuf[t*6+3]; const int bi = __float_as_int(mbuf[t*6+4]); const float b2 = mbuf[t*6+5];
    float v1, v2; int i1;
    if (b1 < a1 || (b1 == a1 && bi < ai)) { v1 = b1; i1 = bi; v2 = fminf(a1, b2); }
    else                                  { v1 = a1; i1 = ai; v2 = fminf(a2, b1); }
    f32x4 st = {v1, (float)i1, v2, 0.f};
    *(f32x4*)&out[PART_OFF + ((size_t)(q0 + t)*2 + ks)*4] = st;
  }
}

// ---------------- merge K-split partials, flag ambiguous queries -------------
__global__ void vq_merge(float* __restrict__ out) {
  const int q = blockIdx.x * 256 + threadIdx.x;
  const f32x4 p0 = *(const f32x4*)&out[PART_OFF + (size_t)q*8 + 0];
  const f32x4 p1 = *(const f32x4*)&out[PART_OFF + (size_t)q*8 + 4];
  const float a1 = p0[0]; const int ai = (int)p0[1]; const float a2 = p0[2];
  const float b1 = p1[0]; const int bi = (int)p1[1]; const float b2 = p1[2];
  float v1, v2; int i1;
  if (b1 < a1 || (b1 == a1 && bi < ai)) { v1 = b1; i1 = bi; v2 = fminf(a1, b2); }
  else                                  { v1 = a1; i1 = ai; v2 = fminf(a2, b1); }
  ((unsigned long long*)&out[KEY_OFF])[q] = ~0ull;
  float enc;
  if (v2 - v1 < TAU) {
    const int pos = atomicAdd((int*)&out[CNT_OFF], 1);
    if (pos < CAPF) ((int*)&out[LIST_OFF])[pos] = q;
    enc = -(float)(i1 + 1);        // flagged: encode negative
  } else enc = (float)i1;
  out[IDX_OFF + q] = enc;
}

// ---------------- exact fp32 re-resolve for flagged queries ------------------
// each block owns 8 codes; deterministic via sortable-key atomicMin (value,index)
__global__ __launch_bounds__(256)
void vq_sweep(const float* __restrict__ x, const float* __restrict__ embed,
              const float* __restrict__ halfe2, float* __restrict__ out) {
  __shared__ float es[8*512];
  __shared__ float xq[512];
  const int t  = threadIdx.x;
  const int kb = blockIdx.x * 8;
  for (int i = t; i < 8*512; i += 256) es[i] = embed[(size_t)kb*512 + i];
  const int nf0 = *(const int*)&out[CNT_OFF];
  const int nf  = nf0 < CAPF ? nf0 : CAPF;
  const int* list = (const int*)&out[LIST_OFF];
  unsigned long long* keys = (unsigned long long*)&out[KEY_OFF];
  const int code = t >> 5, dl = t & 31;
  for (int ii = 0; ii < nf; ++ii) {
    __syncthreads();
    const int q = list[ii];
    const int b = q >> 12, n = q & 4095;
    xq[t]     = x[((size_t)b*DDIM + t)*NNN + n];
    xq[t+256] = x[((size_t)b*DDIM + t + 256)*NNN + n];
    __syncthreads();
    float s = 0.f;
    #pragma unroll
    for (int j = 0; j < 16; ++j) {
      const int d = dl + 32*j;
      s = fmaf(xq[d], es[code*512 + d], s);
    }
    #pragma unroll
    for (int off = 1; off < 32; off <<= 1) s += __shfl_xor(s, off, 64);
    if (dl == 0) {
      const float sc = halfe2[kb + code] - s;
      unsigned u = __float_as_uint(sc);
      u = (u & 0x80000000u) ? ~u : (u | 0x80000000u);   // monotone float->uint
      const unsigned long long key = ((unsigned long long)u << 32) | (unsigned)(kb + code);
      atomicMin(&keys[q], key);
    }
  }
}

// ---------------- apply fixup: decode final indices --------------------------
__global__ void vq_apply(float* __restrict__ out) {
  const int q = blockIdx.x * 256 + threadIdx.x;
  const float enc = out[IDX_OFF + q];
  if (enc < 0.f) {
    const unsigned long long kk = ((const unsigned long long*)&out[KEY_OFF])[q];
    const int k = (kk != ~0ull) ? (int)(unsigned)(kk & 0xFFFFFFFFull) : (int)(-enc) - 1;
    out[IDX_OFF + q] = (float)k;
  }
}

// ---------------- gather quantize rows (overwrites all scratch) --------------
__global__ __launch_bounds__(256)
void vq_gather(const float* __restrict__ embed, float* __restrict__ out) {
  __shared__ int idx_s[64];
  const int t  = threadIdx.x;
  const int q0 = blockIdx.x * 64;
  const int b  = q0 >> 12, n0 = q0 & 4095;
  if (t < 64) idx_s[t] = (int)out[IDX_OFF + q0 + t];
  __syncthreads();
  float* qb = out + (size_t)b*DDIM*NNN + n0;
  for (int l = t; l < DDIM*64; l += 256) {
    const int d = l >> 6, m = l & 63;
    qb[(size_t)d*NNN + m] = embed[(size_t)idx_s[m]*DDIM + d];
  }
}

extern "C" void kernel_launch(void* const* d_in, const int* in_sizes, int n_in,
                              void* d_out, int out_size, void* d_ws, size_t ws_size,
                              hipStream_t stream) {
  const float* x     = (const float*)d_in[0];   // [8, 512, 4096] fp32
  const float* embed = (const float*)d_in[1];   // [2048, 512] fp32
  float* out    = (float*)d_out;
  float* halfe2 = (float*)d_ws;                 // 8 KB scratch (proven safe in R0)

  hipLaunchKernelGGL(e2_half_kernel, dim3(KKK/4), dim3(256), 0, stream, embed, halfe2, out);
  hipLaunchKernelGGL(vq_main,  dim3((MMM/TMQ)*KSPLIT), dim3(256), 0, stream, x, embed, halfe2, out);
  hipLaunchKernelGGL(vq_merge, dim3(MMM/256), dim3(256), 0, stream, out);
  hipLaunchKernelGGL(vq_sweep, dim3(KKK/8),   dim3(256), 0, stream, x, embed, halfe2, out);
  hipLaunchKernelGGL(vq_apply, dim3(MMM/256), dim3(256), 0, stream, out);
  hipLaunchKernelGGL(vq_gather,dim3(MMM/64),  dim3(256), 0, stream, embed, out);
}

// Round 3
// 605.846 us; speedup vs baseline: 1.7371x; 1.4928x over previous
//
#include <hip/hip_runtime.h>
#include <math.h>

#define DDIM 512
#define NNN  4096
#define KKK  2048
#define MMM  32768          // 8*4096 queries

#define TMQ  128            // queries per block (main)
#define TNC  256            // codes per k-tile
#define BK   64             // d per staging round
#define KSPLIT 2
#define KHALF (KKK/KSPLIT)  // 1024
#define NKT  (KHALF/TNC)    // 4
#define NDR  (DDIM/BK)      // 8
#define TAU  0.25f          // flag margin: ~7 sigma of bf16 single-pass score error
#define CAPF 32768

// d_out scratch layout (floats) inside the quantize region [0, 16777216),
// fully overwritten by the final gather:
#define XH_OFF   0                      // x^T as bf16 [m][d]: 16.7M shorts = 8388608 floats
#define EH_OFF   8388608                // embed as bf16 [k][d]: 1M shorts = 524288 floats
#define PART_OFF (EH_OFF + 524288)      // per (q, ks) triple: 32768*2*4 floats
#define LIST_OFF (PART_OFF + 262144)    // flagged-query list (ints)
#define CNT_OFF  (LIST_OFF + CAPF)      // atomic counter (int)
#define IDX_OFF  ((size_t)MMM * DDIM)   // output 1: indices as float

typedef short short8v __attribute__((ext_vector_type(8)));
typedef float f32x4   __attribute__((ext_vector_type(4)));

__device__ inline unsigned short f2bf(float f) {          // fp32 -> bf16 RNE
  unsigned u = __float_as_uint(f);
  u = u + 0x7FFFu + ((u >> 16) & 1u);
  return (unsigned short)(u >> 16);
}

// async global->LDS, 16B per lane; LDS dest = uniform base + lane*16
__device__ inline void gl_lds16(const short* g, short* l) {
  __builtin_amdgcn_global_load_lds(
      (const __attribute__((address_space(1))) unsigned int*)g,
      (__attribute__((address_space(3))) unsigned int*)l, 16, 0, 0);
}

// ---- embed -> bf16 plane + halfe2[k] = 0.5*||e_k||^2 (+ zero flag counter) --
__global__ void conv_e(const float* __restrict__ embed, float* __restrict__ halfe2,
                       float* __restrict__ out) {
  if (blockIdx.x == 0 && threadIdx.x == 0) *(int*)&out[CNT_OFF] = 0;
  const int row  = blockIdx.x * 4 + (threadIdx.x >> 6);
  const int lane = threadIdx.x & 63;
  const float* e = embed + (size_t)row * DDIM;
  short* eh = (short*)&out[EH_OFF];
  const float4 v0 = *(const float4*)&e[lane*8];
  const float4 v1 = *(const float4*)&e[lane*8 + 4];
  const float vv[8] = {v0.x,v0.y,v0.z,v0.w,v1.x,v1.y,v1.z,v1.w};
  float s = 0.f;
  short8v p;
  #pragma unroll
  for (int i = 0; i < 8; ++i) { s = fmaf(vv[i], vv[i], s); p[i] = (short)f2bf(vv[i]); }
  *(short8v*)&eh[(size_t)row * DDIM + lane*8] = p;
  #pragma unroll
  for (int off = 32; off >= 1; off >>= 1) s += __shfl_xor(s, off, 64);
  if (lane == 0) halfe2[row] = 0.5f * s;
}

// ---- x [b][d][n] -> transposed bf16 plane xh[m][d] (m = b*4096+n) ----------
__global__ __launch_bounds__(256)
void conv_x(const float* __restrict__ x, float* __restrict__ out) {
  __shared__ float xt[64][65];          // +1 pad: conflict-free column reads
  const int t  = threadIdx.x;
  const int nt = blockIdx.x & 63, dt = (blockIdx.x >> 6) & 7, b = blockIdx.x >> 9;
  const int n0 = nt * 64, d0 = dt * 64;
  const float* xb = x + ((size_t)b * DDIM + d0) * NNN + n0;
  #pragma unroll
  for (int i = 0; i < 4; ++i) {
    const int fid = t + 256*i;
    const int dl = fid >> 4, n4 = (fid & 15) * 4;
    const float4 v = *(const float4*)&xb[(size_t)dl * NNN + n4];
    xt[dl][n4+0] = v.x; xt[dl][n4+1] = v.y; xt[dl][n4+2] = v.z; xt[dl][n4+3] = v.w;
  }
  __syncthreads();
  short* xh = (short*)&out[XH_OFF];
  const int m0 = b * NNN + n0;
  #pragma unroll
  for (int i = 0; i < 2; ++i) {
    const int id = t + 256*i;
    const int m = id >> 3, ch = (id & 7) * 8;
    short8v p;
    #pragma unroll
    for (int j = 0; j < 8; ++j) p[j] = (short)f2bf(xt[ch + j][m]);
    *(short8v*)&xh[(size_t)(m0 + m) * DDIM + d0 + ch] = p;
  }
}

// ---- main: pure bf16 MFMA GEMM (m97 shape) + fused per-tile argmin ---------
// score[q][k] = 0.5*||e_k||^2 - <x_q, e_k>
__global__ __launch_bounds__(256, 2)
void vq_main(const float* __restrict__ halfe2, float* __restrict__ out) {
  __shared__ __align__(16) short lds[(TMQ + TNC) * BK];   // 48 KB
  short* xs = lds;              // [128 rows][64 d], 128B rows
  short* es = lds + TMQ*BK;     // [256 rows][64 d]
  const short* xh = (const short*)&out[XH_OFF];
  const short* eh = (const short*)&out[EH_OFF];

  const int t  = threadIdx.x;
  const int mb = blockIdx.x >> 1, ks = blockIdx.x & 1;
  const int q0 = mb * TMQ;
  const int kbase = ks * KHALF;
  const int w = t >> 6, lane = t & 63;
  const int mw = (w >> 1) * 64, nw = (w & 1) * 128;   // wave 64x128 sub-tile
  const int l15 = lane & 15, lg = lane >> 4;
  const int c0 = w * 12;
  const int lrow = lane >> 3, lcol = (lane & 7) * 8;  // staging lane map

  // running (best, idx, 2nd-best) for 16 queries/lane (mi x r)
  float rv1[16], rv2[16]; int ri1[16];
  #pragma unroll
  for (int i = 0; i < 16; ++i) { rv1[i] = INFINITY; rv2[i] = INFINITY; ri1[i] = 0x7FFFFFFF; }

  for (int kt = 0; kt < NKT; ++kt) {
    const int kb = kbase + kt * TNC;
    f32x4 acc[4][8];
    #pragma unroll
    for (int mi = 0; mi < 4; ++mi)
      #pragma unroll
      for (int ni = 0; ni < 8; ++ni) acc[mi][ni] = (f32x4){0.f,0.f,0.f,0.f};

    for (int dr = 0; dr < NDR; ++dr) {
      const int d0 = dr * BK;
      __syncthreads();
      // stage 48 KB via global_load_lds: wave w owns chunks [w*12, w*12+12)
      #pragma unroll
      for (int j = 0; j < 12; ++j) {
        const int c = c0 + j;
        if (c < 16) {   // x tile: rows c*8 + lrow
          gl_lds16(xh + (size_t)(q0 + c*8 + lrow) * DDIM + d0 + lcol, &lds[c * 512]);
        } else {        // e tile: rows (c-16)*8 + lrow
          gl_lds16(eh + (size_t)(kb + (c-16)*8 + lrow) * DDIM + d0 + lcol, &lds[c * 512]);
        }
      }
      __syncthreads();
      #pragma unroll
      for (int kk = 0; kk < 2; ++kk) {
        const int dk = kk*32 + lg*8;
        short8v bfr[8];
        #pragma unroll
        for (int ni = 0; ni < 8; ++ni)
          bfr[ni] = *(const short8v*)&es[(nw + ni*16 + l15) * BK + dk];
        #pragma unroll
        for (int mi = 0; mi < 4; ++mi) {
          const short8v a = *(const short8v*)&xs[(mw + mi*16 + l15) * BK + dk];
          #pragma unroll
          for (int ni = 0; ni < 8; ++ni)
            acc[mi][ni] = __builtin_amdgcn_mfma_f32_16x16x32_bf16(a, bfr[ni], acc[mi][ni], 0,0,0);
        }
      }
    }

    // per-k-tile argmin; C/D: col=lane&15 (code), row=lg*4+r (query)
    float he[8];
    #pragma unroll
    for (int ni = 0; ni < 8; ++ni) he[ni] = halfe2[kb + nw + ni*16 + l15];
    #pragma unroll
    for (int mi = 0; mi < 4; ++mi) {
      #pragma unroll
      for (int r = 0; r < 4; ++r) {
        float v1 = INFINITY, v2 = INFINITY; int i1 = 0x7FFFFFFF;
        #pragma unroll
        for (int ni = 0; ni < 8; ++ni) {   // ci ascending: strict < keeps first
          const float sc = he[ni] - acc[mi][ni][r];
          const int   ci = kb + nw + ni*16 + l15;
          if (sc < v1) { v2 = v1; v1 = sc; i1 = ci; }
          else v2 = fminf(v2, sc);
        }
        #pragma unroll
        for (int off = 1; off < 16; off <<= 1) {   // merge 16 code-columns
          const float ov1 = __shfl_xor(v1, off, 64);
          const int   oi1 = __shfl_xor(i1, off, 64);
          const float ov2 = __shfl_xor(v2, off, 64);
          if (ov1 < v1 || (ov1 == v1 && oi1 < i1)) { v2 = fminf(v1, ov2); v1 = ov1; i1 = oi1; }
          else v2 = fminf(v2, ov1);
        }
        const int e_ = mi*4 + r;
        if (v1 < rv1[e_] || (v1 == rv1[e_] && i1 < ri1[e_])) {
          rv2[e_] = fminf(rv1[e_], v2); rv1[e_] = v1; ri1[e_] = i1;
        } else rv2[e_] = fminf(rv2[e_], v1);
      }
    }
  }

  // merge the two code-half waves (w&1) per query via LDS; store partial triple
  __syncthreads();
  float* mbuf = (float*)lds;   // [128 q][2 halves][3]
  if (l15 == 0) {
    #pragma unroll
    for (int mi = 0; mi < 4; ++mi)
      #pragma unroll
      for (int r = 0; r < 4; ++r) {
        const int ql = mw + mi*16 + lg*4 + r;
        const int slot = (ql*2 + (w & 1))*3;
        const int e_ = mi*4 + r;
        mbuf[slot+0] = rv1[e_];
        mbuf[slot+1] = __int_as_float(ri1[e_]);
        mbuf[slot+2] = rv2[e_];
      }
  }
  __syncthreads();
  if (t < TMQ) {
    const float a1 = mbuf[t*6+0]; const int ai = __float_as_int(mbuf[t*6+1]); const float a2 = mbuf[t*6+2];
    const float b1 = mbuf[t*6+3]; const int bi = __float_as_int(mbuf[t*6+4]); const float b2 = mbuf[t*6+5];
    float v1, v2; int i1;
    if (b1 < a1 || (b1 == a1 && bi < ai)) { v1 = b1; i1 = bi; v2 = fminf(a1, b2); }
    else                                  { v1 = a1; i1 = ai; v2 = fminf(a2, b1); }
    f32x4 st = {v1, (float)i1, v2, 0.f};
    *(f32x4*)&out[PART_OFF + ((size_t)(q0 + t)*2 + ks)*4] = st;
  }
}

// ---- merge K-split partials; write index; flag ambiguous queries -----------
__global__ void vq_merge(float* __restrict__ out) {
  const int q = blockIdx.x * 256 + threadIdx.x;
  const f32x4 p0 = *(const f32x4*)&out[PART_OFF + (size_t)q*8 + 0];
  const f32x4 p1 = *(const f32x4*)&out[PART_OFF + (size_t)q*8 + 4];
  const float a1 = p0[0]; const int ai = (int)p0[1]; const float a2 = p0[2];
  const float b1 = p1[0]; const int bi = (int)p1[1]; const float b2 = p1[2];
  float v1, v2; int i1;
  if (b1 < a1 || (b1 == a1 && bi < ai)) { v1 = b1; i1 = bi; v2 = fminf(a1, b2); }
  else                                  { v1 = a1; i1 = ai; v2 = fminf(a2, b1); }
  out[IDX_OFF + q] = (float)i1;
  if (v2 - v1 < TAU) {
    const int pos = atomicAdd((int*)&out[CNT_OFF], 1);
    if (pos < CAPF) ((int*)&out[LIST_OFF])[pos] = q;
  }
}

// ---- exact fp32 re-resolve: 8 flagged queries per block, thread-per-code ---
// queries are block-partitioned -> direct IDX write, no atomics, deterministic
__global__ __launch_bounds__(256)
void vq_sweep(const float* __restrict__ x, const float* __restrict__ embed,
              const float* __restrict__ halfe2, float* __restrict__ out) {
  __shared__ float xq[8 * 520];        // stride 520: 2-way banks only
  __shared__ int   qlist[8];
  __shared__ float rbv[8]; __shared__ int rbi[8];
  __shared__ float wvv[4][8]; __shared__ int wvi[4][8];
  const int t = threadIdx.x, w = t >> 6, lane = t & 63;
  const int nf0 = *(const int*)&out[CNT_OFF];
  const int nf  = nf0 < CAPF ? nf0 : CAPF;
  const int* list = (const int*)&out[LIST_OFF];

  for (int g0 = blockIdx.x * 8; g0 < nf; g0 += 256*8) {
    const int gq = (nf - g0) < 8 ? (nf - g0) : 8;
    __syncthreads();
    if (t < 8) { qlist[t] = list[g0 + (t < gq ? t : 0)]; rbv[t] = INFINITY; rbi[t] = 0; }
    __syncthreads();
    for (int l = t; l < 8*512; l += 256) {
      const int qi = l >> 9, d = l & 511;
      const int q = qlist[qi];
      xq[qi*520 + d] = x[((size_t)(q >> 12) * DDIM + d) * NNN + (q & (NNN-1))];
    }
    __syncthreads();
    for (int kc = 0; kc < 8; ++kc) {
      const int code = kc * 256 + t;
      const float* er = embed + (size_t)code * DDIM;
      float acc[8] = {0.f,0.f,0.f,0.f,0.f,0.f,0.f,0.f};
      for (int d = 0; d < 512; ++d) {
        const float ev = er[d];
        #pragma unroll
        for (int qi = 0; qi < 8; ++qi) acc[qi] = fmaf(xq[qi*520 + d], ev, acc[qi]);
      }
      const float h = halfe2[code];
      #pragma unroll
      for (int qi = 0; qi < 8; ++qi) {
        float v = h - acc[qi]; int ci = code;
        #pragma unroll
        for (int off = 1; off < 64; off <<= 1) {
          const float ov = __shfl_xor(v, off, 64);
          const int   oi = __shfl_xor(ci, off, 64);
          if (ov < v || (ov == v && oi < ci)) { v = ov; ci = oi; }
        }
        if (lane == 0) { wvv[w][qi] = v; wvi[w][qi] = ci; }
      }
      __syncthreads();
      if (t < 8) {
        float v = rbv[t]; int ci = rbi[t];
        #pragma unroll
        for (int ww = 0; ww < 4; ++ww) {
          const float ov = wvv[ww][t]; const int oi = wvi[ww][t];
          if (ov < v || (ov == v && oi < ci)) { v = ov; ci = oi; }
        }
        rbv[t] = v; rbi[t] = ci;
      }
      __syncthreads();
    }
    if (t < gq) out[IDX_OFF + qlist[t]] = (float)rbi[t];
  }
}

// ---- gather quantize rows, float4 stores (overwrites all d_out scratch) ----
__global__ __launch_bounds__(256)
void vq_gather(const float* __restrict__ embed, float* __restrict__ out) {
  __shared__ int idx_s[128];
  const int t  = threadIdx.x;
  const int q0 = blockIdx.x * 128;
  const int b  = q0 >> 12, n0 = q0 & (NNN-1);
  if (t < 128) idx_s[t] = (int)out[IDX_OFF + q0 + t];
  __syncthreads();
  float* qb = out + (size_t)b * DDIM * NNN + n0;
  for (int j = 0; j < 64; ++j) {
    const int id = t + 256*j;
    const int d = id >> 5, n4 = (id & 31) * 4;
    float4 v;
    v.x = embed[(size_t)idx_s[n4+0]*DDIM + d];
    v.y = embed[(size_t)idx_s[n4+1]*DDIM + d];
    v.z = embed[(size_t)idx_s[n4+2]*DDIM + d];
    v.w = embed[(size_t)idx_s[n4+3]*DDIM + d];
    *(float4*)&qb[(size_t)d * NNN + n4] = v;
  }
}

extern "C" void kernel_launch(void* const* d_in, const int* in_sizes, int n_in,
                              void* d_out, int out_size, void* d_ws, size_t ws_size,
                              hipStream_t stream) {
  const float* x     = (const float*)d_in[0];   // [8, 512, 4096] fp32
  const float* embed = (const float*)d_in[1];   // [2048, 512] fp32
  float* out    = (float*)d_out;
  float* halfe2 = (float*)d_ws;                 // 8 KB scratch

  hipLaunchKernelGGL(conv_e,  dim3(KKK/4),  dim3(256), 0, stream, embed, halfe2, out);
  hipLaunchKernelGGL(conv_x,  dim3(4096),   dim3(256), 0, stream, x, out);
  hipLaunchKernelGGL(vq_main, dim3((MMM/TMQ)*KSPLIT), dim3(256), 0, stream, halfe2, out);
  hipLaunchKernelGGL(vq_merge,dim3(MMM/256),dim3(256), 0, stream, out);
  hipLaunchKernelGGL(vq_sweep,dim3(256),    dim3(256), 0, stream, x, embed, halfe2, out);
  hipLaunchKernelGGL(vq_gather,dim3(MMM/128),dim3(256), 0, stream, embed, out);
}

// Round 4
// 396.571 us; speedup vs baseline: 2.6538x; 1.5277x over previous
//
#include <hip/hip_runtime.h>
#include <math.h>

#define DDIM 512
#define NNN  4096
#define KKK  2048
#define MMM  32768          // 8*4096 queries

#define TMQ  128            // queries per block (main)
#define TNC  256            // codes per k-tile (main)
#define BK   64             // d per staging round (main)
#define KSPLIT 2
#define KHALF (KKK/KSPLIT)  // 1024
#define NKT  (KHALF/TNC)    // 4
#define NDR  (DDIM/BK)      // 8
#define TAU  0.25f          // flag margin: ~3 sigma of bf16 single-pass score-diff error
#define CAPF 4096           // flagged-query capacity (expect ~1500)

// d_out scratch layout (floats) inside the quantize region [0, 16777216),
// fully overwritten by the final gather:
#define XH_OFF   0                      // x^T bf16 [m][d]: 16.7M shorts = 8388608 floats
#define EH_OFF   8388608                // embed bf16 [k][d]: 1M shorts = 524288 floats
#define PART_OFF (EH_OFF + 524288)      // per (q,ks) triple: 32768*2*4 = 262144 floats
#define XF_OFF   (PART_OFF + 262144)    // compact fp32 x, transposed [d][slot]: 512*4096
#define KEY_OFF  (XF_OFF + 2097152)     // 4096 u64 = 8192 floats (byte off %8 == 0)
#define LIST_OFF (KEY_OFF + 8192)       // flagged-query list (ints)
#define CNT_OFF  (LIST_OFF + CAPF)      // atomic counter (int)
#define IDX_OFF  ((size_t)MMM * DDIM)   // output 1: indices as float

typedef short short8v __attribute__((ext_vector_type(8)));
typedef float f32x4   __attribute__((ext_vector_type(4)));

__device__ inline unsigned short f2bf(float f) {          // fp32 -> bf16 RNE
  unsigned u = __float_as_uint(f);
  u = u + 0x7FFFu + ((u >> 16) & 1u);
  return (unsigned short)(u >> 16);
}

// async global->LDS, 16B per lane; LDS dest = uniform base + lane*16
__device__ inline void gl_lds16(const short* g, short* l) {
  __builtin_amdgcn_global_load_lds(
      (const __attribute__((address_space(1))) unsigned int*)g,
      (__attribute__((address_space(3))) unsigned int*)l, 16, 0, 0);
}

__device__ inline unsigned mono(float f) {   // monotone float -> uint
  unsigned u = __float_as_uint(f);
  return (u & 0x80000000u) ? ~u : (u | 0x80000000u);
}

// ---- embed -> bf16 plane + halfe2 + init counter/keys ----------------------
__global__ void conv_e(const float* __restrict__ embed, float* __restrict__ halfe2,
                       float* __restrict__ out) {
  const int gid = blockIdx.x * 256 + threadIdx.x;
  if (gid == 0) *(int*)&out[CNT_OFF] = 0;
  if (gid < CAPF) ((unsigned long long*)&out[KEY_OFF])[gid] = ~0ull;
  const int row  = blockIdx.x * 4 + (threadIdx.x >> 6);
  const int lane = threadIdx.x & 63;
  const float* e = embed + (size_t)row * DDIM;
  short* eh = (short*)&out[EH_OFF];
  const float4 v0 = *(const float4*)&e[lane*8];
  const float4 v1 = *(const float4*)&e[lane*8 + 4];
  const float vv[8] = {v0.x,v0.y,v0.z,v0.w,v1.x,v1.y,v1.z,v1.w};
  float s = 0.f;
  short8v p;
  #pragma unroll
  for (int i = 0; i < 8; ++i) { s = fmaf(vv[i], vv[i], s); p[i] = (short)f2bf(vv[i]); }
  *(short8v*)&eh[(size_t)row * DDIM + lane*8] = p;
  #pragma unroll
  for (int off = 32; off >= 1; off >>= 1) s += __shfl_xor(s, off, 64);
  if (lane == 0) halfe2[row] = 0.5f * s;
}

// ---- x [b][d][n] -> transposed bf16 plane xh[m][d] (m = b*4096+n) ----------
__global__ __launch_bounds__(256)
void conv_x(const float* __restrict__ x, float* __restrict__ out) {
  __shared__ float xt[64][65];          // +1 pad: conflict-free column reads
  const int t  = threadIdx.x;
  const int nt = blockIdx.x & 63, dt = (blockIdx.x >> 6) & 7, b = blockIdx.x >> 9;
  const int n0 = nt * 64, d0 = dt * 64;
  const float* xb = x + ((size_t)b * DDIM + d0) * NNN + n0;
  #pragma unroll
  for (int i = 0; i < 4; ++i) {
    const int fid = t + 256*i;
    const int dl = fid >> 4, n4 = (fid & 15) * 4;
    const float4 v = *(const float4*)&xb[(size_t)dl * NNN + n4];
    xt[dl][n4+0] = v.x; xt[dl][n4+1] = v.y; xt[dl][n4+2] = v.z; xt[dl][n4+3] = v.w;
  }
  __syncthreads();
  short* xh = (short*)&out[XH_OFF];
  const int m0 = b * NNN + n0;
  #pragma unroll
  for (int i = 0; i < 2; ++i) {
    const int id = t + 256*i;
    const int m = id >> 3, ch = (id & 7) * 8;
    short8v p;
    #pragma unroll
    for (int j = 0; j < 8; ++j) p[j] = (short)f2bf(xt[ch + j][m]);
    *(short8v*)&xh[(size_t)(m0 + m) * DDIM + d0 + ch] = p;
  }
}

// ---- main: pure bf16 MFMA GEMM (m97 shape) + fused per-tile argmin ---------
// score[q][k] = 0.5*||e_k||^2 - <x_q, e_k>
__global__ __launch_bounds__(256, 2)
void vq_main(const float* __restrict__ halfe2, float* __restrict__ out) {
  __shared__ __align__(16) short lds[(TMQ + TNC) * BK];   // 48 KB
  short* xs = lds;              // [128 rows][64 d]
  short* es = lds + TMQ*BK;     // [256 rows][64 d]
  const short* xh = (const short*)&out[XH_OFF];
  const short* eh = (const short*)&out[EH_OFF];

  const int t  = threadIdx.x;
  const int mb = blockIdx.x >> 1, ks = blockIdx.x & 1;
  const int q0 = mb * TMQ;
  const int kbase = ks * KHALF;
  const int w = t >> 6, lane = t & 63;
  const int mw = (w >> 1) * 64, nw = (w & 1) * 128;   // wave 64x128 sub-tile
  const int l15 = lane & 15, lg = lane >> 4;
  const int c0 = w * 12;
  const int lrow = lane >> 3, lcol = (lane & 7) * 8;  // staging lane map

  float rv1[16], rv2[16]; int ri1[16];
  #pragma unroll
  for (int i = 0; i < 16; ++i) { rv1[i] = INFINITY; rv2[i] = INFINITY; ri1[i] = 0x7FFFFFFF; }

  for (int kt = 0; kt < NKT; ++kt) {
    const int kb = kbase + kt * TNC;
    f32x4 acc[4][8];
    #pragma unroll
    for (int mi = 0; mi < 4; ++mi)
      #pragma unroll
      for (int ni = 0; ni < 8; ++ni) acc[mi][ni] = (f32x4){0.f,0.f,0.f,0.f};

    for (int dr = 0; dr < NDR; ++dr) {
      const int d0 = dr * BK;
      __syncthreads();
      #pragma unroll
      for (int j = 0; j < 12; ++j) {
        const int c = c0 + j;
        if (c < 16) {
          gl_lds16(xh + (size_t)(q0 + c*8 + lrow) * DDIM + d0 + lcol, &lds[c * 512]);
        } else {
          gl_lds16(eh + (size_t)(kb + (c-16)*8 + lrow) * DDIM + d0 + lcol, &lds[c * 512]);
        }
      }
      __syncthreads();
      #pragma unroll
      for (int kk = 0; kk < 2; ++kk) {
        const int dk = kk*32 + lg*8;
        short8v bfr[8];
        #pragma unroll
        for (int ni = 0; ni < 8; ++ni)
          bfr[ni] = *(const short8v*)&es[(nw + ni*16 + l15) * BK + dk];
        #pragma unroll
        for (int mi = 0; mi < 4; ++mi) {
          const short8v a = *(const short8v*)&xs[(mw + mi*16 + l15) * BK + dk];
          #pragma unroll
          for (int ni = 0; ni < 8; ++ni)
            acc[mi][ni] = __builtin_amdgcn_mfma_f32_16x16x32_bf16(a, bfr[ni], acc[mi][ni], 0,0,0);
        }
      }
    }

    float he[8];
    #pragma unroll
    for (int ni = 0; ni < 8; ++ni) he[ni] = halfe2[kb + nw + ni*16 + l15];
    #pragma unroll
    for (int mi = 0; mi < 4; ++mi) {
      #pragma unroll
      for (int r = 0; r < 4; ++r) {
        float v1 = INFINITY, v2 = INFINITY; int i1 = 0x7FFFFFFF;
        #pragma unroll
        for (int ni = 0; ni < 8; ++ni) {   // ci ascending: strict < keeps first
          const float sc = he[ni] - acc[mi][ni][r];
          const int   ci = kb + nw + ni*16 + l15;
          if (sc < v1) { v2 = v1; v1 = sc; i1 = ci; }
          else v2 = fminf(v2, sc);
        }
        #pragma unroll
        for (int off = 1; off < 16; off <<= 1) {
          const float ov1 = __shfl_xor(v1, off, 64);
          const int   oi1 = __shfl_xor(i1, off, 64);
          const float ov2 = __shfl_xor(v2, off, 64);
          if (ov1 < v1 || (ov1 == v1 && oi1 < i1)) { v2 = fminf(v1, ov2); v1 = ov1; i1 = oi1; }
          else v2 = fminf(v2, ov1);
        }
        const int e_ = mi*4 + r;
        if (v1 < rv1[e_] || (v1 == rv1[e_] && i1 < ri1[e_])) {
          rv2[e_] = fminf(rv1[e_], v2); rv1[e_] = v1; ri1[e_] = i1;
        } else rv2[e_] = fminf(rv2[e_], v1);
      }
    }
  }

  __syncthreads();
  float* mbuf = (float*)lds;   // [128 q][2 halves][3]
  if (l15 == 0) {
    #pragma unroll
    for (int mi = 0; mi < 4; ++mi)
      #pragma unroll
      for (int r = 0; r < 4; ++r) {
        const int ql = mw + mi*16 + lg*4 + r;
        const int slot = (ql*2 + (w & 1))*3;
        const int e_ = mi*4 + r;
        mbuf[slot+0] = rv1[e_];
        mbuf[slot+1] = __int_as_float(ri1[e_]);
        mbuf[slot+2] = rv2[e_];
      }
  }
  __syncthreads();
  if (t < TMQ) {
    const float a1 = mbuf[t*6+0]; const int ai = __float_as_int(mbuf[t*6+1]); const float a2 = mbuf[t*6+2];
    const float b1 = mbuf[t*6+3]; const int bi = __float_as_int(mbuf[t*6+4]); const float b2 = mbuf[t*6+5];
    float v1, v2; int i1;
    if (b1 < a1 || (b1 == a1 && bi < ai)) { v1 = b1; i1 = bi; v2 = fminf(a1, b2); }
    else                                  { v1 = a1; i1 = ai; v2 = fminf(a2, b1); }
    f32x4 st = {v1, (float)i1, v2, 0.f};
    *(f32x4*)&out[PART_OFF + ((size_t)(q0 + t)*2 + ks)*4] = st;
  }
}

// ---- merge K-split partials; write index; flag ambiguous queries -----------
__global__ void vq_merge(float* __restrict__ out) {
  const int q = blockIdx.x * 256 + threadIdx.x;
  const f32x4 p0 = *(const f32x4*)&out[PART_OFF + (size_t)q*8 + 0];
  const f32x4 p1 = *(const f32x4*)&out[PART_OFF + (size_t)q*8 + 4];
  const float a1 = p0[0]; const int ai = (int)p0[1]; const float a2 = p0[2];
  const float b1 = p1[0]; const int bi = (int)p1[1]; const float b2 = p1[2];
  float v1, v2; int i1;
  if (b1 < a1 || (b1 == a1 && bi < ai)) { v1 = b1; i1 = bi; v2 = fminf(a1, b2); }
  else                                  { v1 = a1; i1 = ai; v2 = fminf(a2, b1); }
  out[IDX_OFF + q] = (float)i1;
  if (v2 - v1 < TAU) {
    const int pos = atomicAdd((int*)&out[CNT_OFF], 1);
    if (pos < CAPF) ((int*)&out[LIST_OFF])[pos] = q;
  }
}

// ---- prep: compact flagged x rows into transposed fp32 plane XF[d][slot] ---
// x is L3-resident (just streamed by conv_x); scattered 4B accesses OK.
__global__ __launch_bounds__(256)
void vq_prep(const float* __restrict__ x, float* __restrict__ out) {
  const int nf0 = *(const int*)&out[CNT_OFF];
  const int nf  = nf0 < CAPF ? nf0 : CAPF;
  const int* list = (const int*)&out[LIST_OFF];
  float* XF = &out[XF_OFF];
  const int wid  = (blockIdx.x * 256 + threadIdx.x) >> 6;   // 1024 waves
  const int lane = threadIdx.x & 63;
  for (int s = wid; s < nf; s += 1024) {
    const int q = list[s];
    const int b = q >> 12, n = q & (NNN - 1);
    const float* xb = x + (size_t)b * DDIM * NNN + n;
    #pragma unroll
    for (int j = 0; j < 8; ++j) {
      const int d = lane + 64*j;
      XF[(size_t)d * CAPF + s] = xb[(size_t)d * NNN];
    }
  }
}

// ---- refine: exact fp32 microtile GEMM over flagged slots ------------------
// block = 64 slots x 128 codes; 4x8 register microtile (R0-proven geometry);
// deterministic cross-block merge via monotone-key atomicMin.
__global__ __launch_bounds__(256, 2)
void vq_refine(const float* __restrict__ embed, const float* __restrict__ halfe2,
               float* __restrict__ out) {
  const int nf0 = *(const int*)&out[CNT_OFF];
  const int nf  = nf0 < CAPF ? nf0 : CAPF;
  const int s0  = blockIdx.y * 64;
  if (s0 >= nf) return;
  __shared__ float xs[32][64];
  __shared__ float es[32][132];
  const int t = threadIdx.x, tx = t & 15, ty = t >> 4;
  const int kb = blockIdx.x * 128;
  const float* XF = &out[XF_OFF];
  unsigned long long* keys = (unsigned long long*)&out[KEY_OFF];

  float acc[4][8];
  #pragma unroll
  for (int i = 0; i < 4; ++i)
    #pragma unroll
    for (int j = 0; j < 8; ++j) acc[i][j] = 0.f;

  for (int dc = 0; dc < 16; ++dc) {
    __syncthreads();
    #pragma unroll
    for (int i = 0; i < 8; ++i) {        // xs[d][m] <- XF[d][s0+m], coalesced over m
      const int l = t + 256*i;
      const int d = l >> 6, m = l & 63;
      xs[d][m] = XF[(size_t)(dc*32 + d) * CAPF + s0 + m];
    }
    #pragma unroll
    for (int i = 0; i < 4; ++i) {        // es[d][k] <- embed rows (float4)
      const int l = t + 256*i;
      const int k = l >> 3, f = l & 7;
      const float4 v = *(const float4*)&embed[(size_t)(kb + k)*DDIM + dc*32 + 4*f];
      es[4*f+0][k] = v.x; es[4*f+1][k] = v.y; es[4*f+2][k] = v.z; es[4*f+3][k] = v.w;
    }
    __syncthreads();
    #pragma unroll
    for (int d = 0; d < 32; ++d) {       // sequential d: deterministic sum order
      const float4 a4 = *(const float4*)&xs[d][ty*4];
      const float4 b0 = *(const float4*)&es[d][tx*4];
      const float4 b1 = *(const float4*)&es[d][64 + tx*4];
      const float a[4]  = {a4.x, a4.y, a4.z, a4.w};
      const float bb[8] = {b0.x, b0.y, b0.z, b0.w, b1.x, b1.y, b1.z, b1.w};
      #pragma unroll
      for (int i = 0; i < 4; ++i)
        #pragma unroll
        for (int j = 0; j < 8; ++j)
          acc[i][j] = fmaf(a[i], bb[j], acc[i][j]);
    }
  }

  const int kb0 = kb + tx*4, kb1 = kb + 64 + tx*4;
  const float4 h0 = *(const float4*)&halfe2[kb0];
  const float4 h1 = *(const float4*)&halfe2[kb1];
  const float hh[8] = {h0.x, h0.y, h0.z, h0.w, h1.x, h1.y, h1.z, h1.w};
  #pragma unroll
  for (int i = 0; i < 4; ++i) {
    float v = hh[0] - acc[i][0];
    int  vi = kb0;
    #pragma unroll
    for (int j = 1; j < 8; ++j) {
      const float w  = hh[j] - acc[i][j];
      const int   wk = (j < 4) ? (kb0 + j) : (kb1 + j - 4);
      if (w < v) { v = w; vi = wk; }     // ascending codes: strict < keeps first
    }
    #pragma unroll
    for (int off = 1; off < 16; off <<= 1) {
      const float ov = __shfl_xor(v, off, 64);
      const int   oi = __shfl_xor(vi, off, 64);
      if (ov < v || (ov == v && oi < vi)) { v = ov; vi = oi; }
    }
    if (tx == 0) {
      const unsigned long long key =
          ((unsigned long long)mono(v) << 32) | (unsigned)vi;
      atomicMin(&keys[s0 + ty*4 + i], key);
    }
  }
}

// ---- apply: decode refined keys back into IDX ------------------------------
__global__ void vq_apply(float* __restrict__ out) {
  const int slot = blockIdx.x * 256 + threadIdx.x;
  const int nf0 = *(const int*)&out[CNT_OFF];
  const int nf  = nf0 < CAPF ? nf0 : CAPF;
  if (slot >= nf) return;
  const int q = ((const int*)&out[LIST_OFF])[slot];
  const unsigned long long k = ((const unsigned long long*)&out[KEY_OFF])[slot];
  if (k != ~0ull) out[IDX_OFF + q] = (float)(unsigned)(k & 0xFFFFFFFFull);
}

// ---- gather quantize rows, float4 stores (overwrites all d_out scratch) ----
__global__ __launch_bounds__(256)
void vq_gather(const float* __restrict__ embed, float* __restrict__ out) {
  __shared__ int idx_s[128];
  const int t  = threadIdx.x;
  const int q0 = blockIdx.x * 128;
  const int b  = q0 >> 12, n0 = q0 & (NNN-1);
  if (t < 128) idx_s[t] = (int)out[IDX_OFF + q0 + t];
  __syncthreads();
  float* qb = out + (size_t)b * DDIM * NNN + n0;
  for (int j = 0; j < 64; ++j) {
    const int id = t + 256*j;
    const int d = id >> 5, n4 = (id & 31) * 4;
    float4 v;
    v.x = embed[(size_t)idx_s[n4+0]*DDIM + d];
    v.y = embed[(size_t)idx_s[n4+1]*DDIM + d];
    v.z = embed[(size_t)idx_s[n4+2]*DDIM + d];
    v.w = embed[(size_t)idx_s[n4+3]*DDIM + d];
    *(float4*)&qb[(size_t)d * NNN + n4] = v;
  }
}

extern "C" void kernel_launch(void* const* d_in, const int* in_sizes, int n_in,
                              void* d_out, int out_size, void* d_ws, size_t ws_size,
                              hipStream_t stream) {
  const float* x     = (const float*)d_in[0];   // [8, 512, 4096] fp32
  const float* embed = (const float*)d_in[1];   // [2048, 512] fp32
  float* out    = (float*)d_out;
  float* halfe2 = (float*)d_ws;                 // 8 KB scratch

  hipLaunchKernelGGL(conv_e,   dim3(KKK/4),   dim3(256), 0, stream, embed, halfe2, out);
  hipLaunchKernelGGL(conv_x,   dim3(4096),    dim3(256), 0, stream, x, out);
  hipLaunchKernelGGL(vq_main,  dim3((MMM/TMQ)*KSPLIT), dim3(256), 0, stream, halfe2, out);
  hipLaunchKernelGGL(vq_merge, dim3(MMM/256), dim3(256), 0, stream, out);
  hipLaunchKernelGGL(vq_prep,  dim3(256),     dim3(256), 0, stream, x, out);
  hipLaunchKernelGGL(vq_refine,dim3(16, CAPF/64), dim3(256), 0, stream, embed, halfe2, out);
  hipLaunchKernelGGL(vq_apply, dim3(CAPF/256),dim3(256), 0, stream, out);
  hipLaunchKernelGGL(vq_gather,dim3(MMM/128), dim3(256), 0, stream, embed, out);
}

// Round 5
// 348.608 us; speedup vs baseline: 3.0189x; 1.1376x over previous
//
#include <hip/hip_runtime.h>
#include <math.h>

#define DDIM 512
#define NNN  4096
#define KKK  2048
#define MMM  32768          // 8*4096 queries

#define TMQ  128            // queries per block (main)
#define TNC  256            // codes per k-tile (main)
#define BK   64             // d per staging round (main)
#define KSPLIT 2
#define KHALF (KKK/KSPLIT)  // 1024
#define NKT  (KHALF/TNC)    // 4
#define NDR  (DDIM/BK)      // 8
#define TAU  0.25f          // flag margin for exact re-resolve
#define CAPF 4096           // flagged-query capacity

// d_out scratch layout (floats) inside the quantize region [0, 16777216),
// fully overwritten by the final gather:
#define XH_OFF   0                      // x^T bf16 [m][d]: 8388608 floats
#define EH_OFF   8388608                // embed bf16 [k][d]: 524288 floats
#define PART_OFF (EH_OFF + 524288)      // per (q,ks) triple: 262144 floats
#define XF_OFF   (PART_OFF + 262144)    // compact fp32 x [slot][d]: CAPF*512
#define KEY_OFF  (XF_OFF + 2097152)     // CAPF u64 keys (byte off %8 == 0)
#define LIST_OFF (KEY_OFF + 8192)       // flagged-query list (ints)
#define CNT_OFF  (LIST_OFF + CAPF)      // atomic counter (int)
#define IDX_OFF  ((size_t)MMM * DDIM)   // output 1: indices as float

typedef short short8v __attribute__((ext_vector_type(8)));
typedef float f32x4   __attribute__((ext_vector_type(4)));

__device__ inline unsigned short f2bf(float f) {          // fp32 -> bf16 RNE
  unsigned u = __float_as_uint(f);
  u = u + 0x7FFFu + ((u >> 16) & 1u);
  return (unsigned short)(u >> 16);
}

// async global->LDS, 16B per lane; LDS dest = uniform base + lane*16
__device__ inline void gl_lds16(const short* g, short* l) {
  __builtin_amdgcn_global_load_lds(
      (const __attribute__((address_space(1))) unsigned int*)g,
      (__attribute__((address_space(3))) unsigned int*)l, 16, 0, 0);
}

__device__ inline unsigned mono(float f) {   // monotone float -> uint
  unsigned u = __float_as_uint(f);
  return (u & 0x80000000u) ? ~u : (u | 0x80000000u);
}

// XOR-swizzled frag-read short-index into a [rows][64-short] tile:
// physical 16B-quad = (dk>>3) ^ (row&7). Kills the 16-way conflicts of the
// linear layout (row stride 128 B == 0 mod 32 banks); 16 lanes now spread
// over 8 bank-quads = 2-way (free, m136).
__device__ inline int fswz(int row, int dk) {
  return row*64 + ((((dk >> 3) ^ (row & 7)) << 3));
}

// ---- embed -> bf16 plane + halfe2 + init counter/keys ----------------------
__global__ void conv_e(const float* __restrict__ embed, float* __restrict__ halfe2,
                       float* __restrict__ out) {
  const int gid = blockIdx.x * 256 + threadIdx.x;
  if (gid == 0) *(int*)&out[CNT_OFF] = 0;
  if (gid < CAPF) ((unsigned long long*)&out[KEY_OFF])[gid] = ~0ull;
  const int row  = blockIdx.x * 4 + (threadIdx.x >> 6);
  const int lane = threadIdx.x & 63;
  const float* e = embed + (size_t)row * DDIM;
  short* eh = (short*)&out[EH_OFF];
  const float4 v0 = *(const float4*)&e[lane*8];
  const float4 v1 = *(const float4*)&e[lane*8 + 4];
  const float vv[8] = {v0.x,v0.y,v0.z,v0.w,v1.x,v1.y,v1.z,v1.w};
  float s = 0.f;
  short8v p;
  #pragma unroll
  for (int i = 0; i < 8; ++i) { s = fmaf(vv[i], vv[i], s); p[i] = (short)f2bf(vv[i]); }
  *(short8v*)&eh[(size_t)row * DDIM + lane*8] = p;
  #pragma unroll
  for (int off = 32; off >= 1; off >>= 1) s += __shfl_xor(s, off, 64);
  if (lane == 0) halfe2[row] = 0.5f * s;
}

// ---- x [b][d][n] -> transposed bf16 plane xh[m][d] (m = b*4096+n) ----------
__global__ __launch_bounds__(256)
void conv_x(const float* __restrict__ x, float* __restrict__ out) {
  __shared__ float xt[64][65];          // +1 pad: conflict-free column reads
  const int t  = threadIdx.x;
  const int nt = blockIdx.x & 63, dt = (blockIdx.x >> 6) & 7, b = blockIdx.x >> 9;
  const int n0 = nt * 64, d0 = dt * 64;
  const float* xb = x + ((size_t)b * DDIM + d0) * NNN + n0;
  #pragma unroll
  for (int i = 0; i < 4; ++i) {
    const int fid = t + 256*i;
    const int dl = fid >> 4, n4 = (fid & 15) * 4;
    const float4 v = *(const float4*)&xb[(size_t)dl * NNN + n4];
    xt[dl][n4+0] = v.x; xt[dl][n4+1] = v.y; xt[dl][n4+2] = v.z; xt[dl][n4+3] = v.w;
  }
  __syncthreads();
  short* xh = (short*)&out[XH_OFF];
  const int m0 = b * NNN + n0;
  #pragma unroll
  for (int i = 0; i < 2; ++i) {
    const int id = t + 256*i;
    const int m = id >> 3, ch = (id & 7) * 8;
    short8v p;
    #pragma unroll
    for (int j = 0; j < 8; ++j) p[j] = (short)f2bf(xt[ch + j][m]);
    *(short8v*)&xh[(size_t)(m0 + m) * DDIM + d0 + ch] = p;
  }
}

// ---- main: pure bf16 MFMA GEMM + deferred fused argmin ---------------------
// score[q][k] = 0.5*||e_k||^2 - <x_q, e_k>
__global__ __launch_bounds__(256, 2)
void vq_main(const float* __restrict__ halfe2, float* __restrict__ out) {
  __shared__ __align__(16) short lds[(TMQ + TNC) * BK];   // 48 KB
  short* xs = lds;              // [128 rows][64 d], XOR-swizzled quads
  short* es = lds + TMQ*BK;     // [256 rows][64 d], XOR-swizzled quads
  const short* xh = (const short*)&out[XH_OFF];
  const short* eh = (const short*)&out[EH_OFF];

  const int t  = threadIdx.x;
  const int mb = blockIdx.x >> 1, ks = blockIdx.x & 1;
  const int q0 = mb * TMQ;
  const int kbase = ks * KHALF;
  const int w = t >> 6, lane = t & 63;
  const int mw = (w >> 1) * 64, nw = (w & 1) * 128;   // wave 64x128 sub-tile
  const int l15 = lane & 15, lg = lane >> 4;
  const int c0 = w * 12;
  const int lrow = lane >> 3;                          // staging row within chunk
  const int scol = (((lane & 7) ^ lrow) << 3);         // swizzled source quad

  // deferred per-lane running (best, idx, 2nd-best) for 16 queries/lane
  float rv1[16], rv2[16]; int ri1[16];
  #pragma unroll
  for (int i = 0; i < 16; ++i) { rv1[i] = INFINITY; rv2[i] = INFINITY; ri1[i] = 0x7FFFFFFF; }

  for (int kt = 0; kt < NKT; ++kt) {
    const int kb = kbase + kt * TNC;
    f32x4 acc[4][8];
    #pragma unroll
    for (int mi = 0; mi < 4; ++mi)
      #pragma unroll
      for (int ni = 0; ni < 8; ++ni) acc[mi][ni] = (f32x4){0.f,0.f,0.f,0.f};

    for (int dr = 0; dr < NDR; ++dr) {
      const int d0 = dr * BK;
      __syncthreads();
      // stage 48 KB via global_load_lds; swizzle folded into source column
      #pragma unroll
      for (int j = 0; j < 12; ++j) {
        const int c = c0 + j;
        if (c < 16) {
          gl_lds16(xh + (size_t)(q0 + c*8 + lrow) * DDIM + d0 + scol, &lds[c * 512]);
        } else {
          gl_lds16(eh + (size_t)(kb + (c-16)*8 + lrow) * DDIM + d0 + scol, &lds[c * 512]);
        }
      }
      __syncthreads();
      #pragma unroll
      for (int kk = 0; kk < 2; ++kk) {
        const int dk = kk*32 + lg*8;
        short8v bfr[8];
        #pragma unroll
        for (int ni = 0; ni < 8; ++ni)
          bfr[ni] = *(const short8v*)&es[fswz(nw + ni*16 + l15, dk)];
        #pragma unroll
        for (int mi = 0; mi < 4; ++mi) {
          const short8v a = *(const short8v*)&xs[fswz(mw + mi*16 + l15, dk)];
          #pragma unroll
          for (int ni = 0; ni < 8; ++ni)
            acc[mi][ni] = __builtin_amdgcn_mfma_f32_16x16x32_bf16(a, bfr[ni], acc[mi][ni], 0,0,0);
        }
      }
    }

    // per-k-tile: per-lane tournament only (no cross-lane traffic);
    // candidate indices strictly ascend -> strict < keeps first index
    float he[8];
    #pragma unroll
    for (int ni = 0; ni < 8; ++ni) he[ni] = halfe2[kb + nw + ni*16 + l15];
    #pragma unroll
    for (int mi = 0; mi < 4; ++mi) {
      #pragma unroll
      for (int r = 0; r < 4; ++r) {
        const int e_ = mi*4 + r;
        #pragma unroll
        for (int ni = 0; ni < 8; ++ni) {
          const float sc = he[ni] - acc[mi][ni][r];
          if (sc < rv1[e_]) { rv2[e_] = rv1[e_]; rv1[e_] = sc; ri1[e_] = kb + nw + ni*16 + l15; }
          else rv2[e_] = fminf(rv2[e_], sc);
        }
      }
    }
  }

  // once: cross-lane merge over the 16 code-columns (within each 16-lane group)
  #pragma unroll
  for (int e_ = 0; e_ < 16; ++e_) {
    float v1 = rv1[e_], v2 = rv2[e_]; int i1 = ri1[e_];
    #pragma unroll
    for (int off = 1; off < 16; off <<= 1) {
      const float ov1 = __shfl_xor(v1, off, 64);
      const int   oi1 = __shfl_xor(i1, off, 64);
      const float ov2 = __shfl_xor(v2, off, 64);
      if (ov1 < v1 || (ov1 == v1 && oi1 < i1)) { v2 = fminf(v1, ov2); v1 = ov1; i1 = oi1; }
      else v2 = fminf(v2, ov1);
    }
    rv1[e_] = v1; rv2[e_] = v2; ri1[e_] = i1;
  }

  // merge the two code-half waves (w&1) per query via LDS; store partial triple
  __syncthreads();
  float* mbuf = (float*)lds;   // [128 q][2 halves][3]
  if (l15 == 0) {
    #pragma unroll
    for (int mi = 0; mi < 4; ++mi)
      #pragma unroll
      for (int r = 0; r < 4; ++r) {
        const int ql = mw + mi*16 + lg*4 + r;
        const int slot = (ql*2 + (w & 1))*3;
        const int e_ = mi*4 + r;
        mbuf[slot+0] = rv1[e_];
        mbuf[slot+1] = __int_as_float(ri1[e_]);
        mbuf[slot+2] = rv2[e_];
      }
  }
  __syncthreads();
  if (t < TMQ) {
    const float a1 = mbuf[t*6+0]; const int ai = __float_as_int(mbuf[t*6+1]); const float a2 = mbuf[t*6+2];
    const float b1 = mbuf[t*6+3]; const int bi = __float_as_int(mbuf[t*6+4]); const float b2 = mbuf[t*6+5];
    float v1, v2; int i1;
    if (b1 < a1 || (b1 == a1 && bi < ai)) { v1 = b1; i1 = bi; v2 = fminf(a1, b2); }
    else                                  { v1 = a1; i1 = ai; v2 = fminf(a2, b1); }
    f32x4 st = {v1, (float)i1, v2, 0.f};
    *(f32x4*)&out[PART_OFF + ((size_t)(q0 + t)*2 + ks)*4] = st;
  }
}

// ---- merge K-split partials; write index; flag ambiguous queries -----------
__global__ void vq_merge(float* __restrict__ out) {
  const int q = blockIdx.x * 256 + threadIdx.x;
  const f32x4 p0 = *(const f32x4*)&out[PART_OFF + (size_t)q*8 + 0];
  const f32x4 p1 = *(const f32x4*)&out[PART_OFF + (size_t)q*8 + 4];
  const float a1 = p0[0]; const int ai = (int)p0[1]; const float a2 = p0[2];
  const float b1 = p1[0]; const int bi = (int)p1[1]; const float b2 = p1[2];
  float v1, v2; int i1;
  if (b1 < a1 || (b1 == a1 && bi < ai)) { v1 = b1; i1 = bi; v2 = fminf(a1, b2); }
  else                                  { v1 = a1; i1 = ai; v2 = fminf(a2, b1); }
  out[IDX_OFF + q] = (float)i1;
  if (v2 - v1 < TAU) {
    const int pos = atomicAdd((int*)&out[CNT_OFF], 1);
    if (pos < CAPF) ((int*)&out[LIST_OFF])[pos] = q;
  }
}

// ---- prep: compact flagged x rows into fp32 plane XF[slot][d] --------------
// reads scattered (inherent to x layout, L3-resident); writes coalesced 256B/wave
__global__ __launch_bounds__(256)
void vq_prep(const float* __restrict__ x, float* __restrict__ out) {
  const int nf0 = *(const int*)&out[CNT_OFF];
  const int nf  = nf0 < CAPF ? nf0 : CAPF;
  const int* list = (const int*)&out[LIST_OFF];
  float* XF = &out[XF_OFF];
  const int wid  = (blockIdx.x * 256 + threadIdx.x) >> 6;   // 1024 waves
  const int lane = threadIdx.x & 63;
  for (int s = wid; s < nf; s += 1024) {
    const int q = list[s];
    const int b = q >> 12, n = q & (NNN - 1);
    const float* xb = x + (size_t)b * DDIM * NNN + n;
    #pragma unroll
    for (int j = 0; j < 8; ++j) {
      const int d = lane + 64*j;
      XF[(size_t)s * DDIM + d] = xb[(size_t)d * NNN];
    }
  }
}

// ---- refine: exact fp32 microtile GEMM over flagged slots ------------------
// block = 64 slots x 128 codes; 4x8 register microtile;
// deterministic cross-block merge via monotone-key atomicMin.
__global__ __launch_bounds__(256, 2)
void vq_refine(const float* __restrict__ embed, const float* __restrict__ halfe2,
               float* __restrict__ out) {
  const int nf0 = *(const int*)&out[CNT_OFF];
  const int nf  = nf0 < CAPF ? nf0 : CAPF;
  const int s0  = blockIdx.y * 64;
  if (s0 >= nf) return;
  __shared__ float xs[32][68];   // stride 68: float4-aligned, <=4-way stage writes
  __shared__ float es[32][132];
  const int t = threadIdx.x, tx = t & 15, ty = t >> 4;
  const int kb = blockIdx.x * 128;
  const float* XF = &out[XF_OFF];
  unsigned long long* keys = (unsigned long long*)&out[KEY_OFF];

  float acc[4][8];
  #pragma unroll
  for (int i = 0; i < 4; ++i)
    #pragma unroll
    for (int j = 0; j < 8; ++j) acc[i][j] = 0.f;

  for (int dc = 0; dc < 16; ++dc) {
    __syncthreads();
    #pragma unroll
    for (int i = 0; i < 2; ++i) {        // xs[d][m] <- XF[s0+m][.] row float4 reads
      const int l = t + 256*i;           // 512 float4
      const int m = l >> 3, f = l & 7;
      const float4 v = *(const float4*)&XF[(size_t)(s0 + m) * DDIM + dc*32 + 4*f];
      xs[4*f+0][m] = v.x; xs[4*f+1][m] = v.y; xs[4*f+2][m] = v.z; xs[4*f+3][m] = v.w;
    }
    #pragma unroll
    for (int i = 0; i < 4; ++i) {        // es[d][k] <- embed rows (float4)
      const int l = t + 256*i;
      const int k = l >> 3, f = l & 7;
      const float4 v = *(const float4*)&embed[(size_t)(kb + k)*DDIM + dc*32 + 4*f];
      es[4*f+0][k] = v.x; es[4*f+1][k] = v.y; es[4*f+2][k] = v.z; es[4*f+3][k] = v.w;
    }
    __syncthreads();
    #pragma unroll
    for (int d = 0; d < 32; ++d) {       // sequential d: deterministic sum order
      const float4 a4 = *(const float4*)&xs[d][ty*4];
      const float4 b0 = *(const float4*)&es[d][tx*4];
      const float4 b1 = *(const float4*)&es[d][64 + tx*4];
      const float a[4]  = {a4.x, a4.y, a4.z, a4.w};
      const float bb[8] = {b0.x, b0.y, b0.z, b0.w, b1.x, b1.y, b1.z, b1.w};
      #pragma unroll
      for (int i = 0; i < 4; ++i)
        #pragma unroll
        for (int j = 0; j < 8; ++j)
          acc[i][j] = fmaf(a[i], bb[j], acc[i][j]);
    }
  }

  const int kb0 = kb + tx*4, kb1 = kb + 64 + tx*4;
  const float4 h0 = *(const float4*)&halfe2[kb0];
  const float4 h1 = *(const float4*)&halfe2[kb1];
  const float hh[8] = {h0.x, h0.y, h0.z, h0.w, h1.x, h1.y, h1.z, h1.w};
  #pragma unroll
  for (int i = 0; i < 4; ++i) {
    float v = hh[0] - acc[i][0];
    int  vi = kb0;
    #pragma unroll
    for (int j = 1; j < 8; ++j) {
      const float w  = hh[j] - acc[i][j];
      const int   wk = (j < 4) ? (kb0 + j) : (kb1 + j - 4);
      if (w < v) { v = w; vi = wk; }     // ascending codes: strict < keeps first
    }
    #pragma unroll
    for (int off = 1; off < 16; off <<= 1) {
      const float ov = __shfl_xor(v, off, 64);
      const int   oi = __shfl_xor(vi, off, 64);
      if (ov < v || (ov == v && oi < vi)) { v = ov; vi = oi; }
    }
    if (tx == 0) {
      const unsigned long long key =
          ((unsigned long long)mono(v) << 32) | (unsigned)vi;
      atomicMin(&keys[s0 + ty*4 + i], key);
    }
  }
}

// ---- apply: decode refined keys back into IDX ------------------------------
__global__ void vq_apply(float* __restrict__ out) {
  const int slot = blockIdx.x * 256 + threadIdx.x;
  const int nf0 = *(const int*)&out[CNT_OFF];
  const int nf  = nf0 < CAPF ? nf0 : CAPF;
  if (slot >= nf) return;
  const int q = ((const int*)&out[LIST_OFF])[slot];
  const unsigned long long k = ((const unsigned long long*)&out[KEY_OFF])[slot];
  if (k != ~0ull) out[IDX_OFF + q] = (float)(unsigned)(k & 0xFFFFFFFFull);
}

// ---- gather quantize rows, float4 stores (overwrites all d_out scratch) ----
__global__ __launch_bounds__(256)
void vq_gather(const float* __restrict__ embed, float* __restrict__ out) {
  __shared__ int idx_s[128];
  const int t  = threadIdx.x;
  const int q0 = blockIdx.x * 128;
  const int b  = q0 >> 12, n0 = q0 & (NNN-1);
  if (t < 128) idx_s[t] = (int)out[IDX_OFF + q0 + t];
  __syncthreads();
  float* qb = out + (size_t)b * DDIM * NNN + n0;
  for (int j = 0; j < 64; ++j) {
    const int id = t + 256*j;
    const int d = id >> 5, n4 = (id & 31) * 4;
    float4 v;
    v.x = embed[(size_t)idx_s[n4+0]*DDIM + d];
    v.y = embed[(size_t)idx_s[n4+1]*DDIM + d];
    v.z = embed[(size_t)idx_s[n4+2]*DDIM + d];
    v.w = embed[(size_t)idx_s[n4+3]*DDIM + d];
    *(float4*)&qb[(size_t)d * NNN + n4] = v;
  }
}

extern "C" void kernel_launch(void* const* d_in, const int* in_sizes, int n_in,
                              void* d_out, int out_size, void* d_ws, size_t ws_size,
                              hipStream_t stream) {
  const float* x     = (const float*)d_in[0];   // [8, 512, 4096] fp32
  const float* embed = (const float*)d_in[1];   // [2048, 512] fp32
  float* out    = (float*)d_out;
  float* halfe2 = (float*)d_ws;                 // 8 KB scratch

  hipLaunchKernelGGL(conv_e,   dim3(KKK/4),   dim3(256), 0, stream, embed, halfe2, out);
  hipLaunchKernelGGL(conv_x,   dim3(4096),    dim3(256), 0, stream, x, out);
  hipLaunchKernelGGL(vq_main,  dim3((MMM/TMQ)*KSPLIT), dim3(256), 0, stream, halfe2, out);
  hipLaunchKernelGGL(vq_merge, dim3(MMM/256), dim3(256), 0, stream, out);
  hipLaunchKernelGGL(vq_prep,  dim3(256),     dim3(256), 0, stream, x, out);
  hipLaunchKernelGGL(vq_refine,dim3(16, CAPF/64), dim3(256), 0, stream, embed, halfe2, out);
  hipLaunchKernelGGL(vq_apply, dim3(CAPF/256),dim3(256), 0, stream, out);
  hipLaunchKernelGGL(vq_gather,dim3(MMM/128), dim3(256), 0, stream, embed, out);
}